// Round 4
// baseline (4216.589 us; speedup 1.0000x reference)
//
#include <hip/hip_runtime.h>
#include <hip/hip_bf16.h>
#include <cstdio>

#define C_    320
#define H_    56
#define W_    100
#define P_    5600           // H_*W_
#define MM    6
#define BB    2
#define NIMG  12             // BB*MM
#define NTOT  67200          // NIMG*P_
#define NHEADS 10

// ---------------------------------------------------------------------------
// Static device workspace: 5 activation slots + attn weights + fused W1.
// Allocated at module load; independent of harness ws_size.
// (Round 4 = round 3 resubmitted verbatim after GPU-acquisition timeout.)
// ---------------------------------------------------------------------------
#define SLOT  ((size_t)NTOT * C_)                 // 21,504,000 floats
#define WS_FLOATS (5 * SLOT + (size_t)2 * NHEADS * NTOT + (size_t)C_ * C_)
__device__ float g_ws[WS_FLOATS];

// ---------------------------------------------------------------------------
// W1f[ci][co] = sum_k a1_wv[ci][k] * a1_wo[k][co]   (attn1 collapses to this)
// ---------------------------------------------------------------------------
__global__ void fuse_w1_kernel(const float* __restrict__ wv,
                               const float* __restrict__ wo,
                               float* __restrict__ w1f) {
  int ci = blockIdx.x;
  int co = threadIdx.x;
  float acc = 0.f;
  for (int k = 0; k < C_; ++k)
    acc = fmaf(wv[ci * C_ + k], wo[k * C_ + co], acc);
  w1f[ci * C_ + co] = acc;
}

// ---------------------------------------------------------------------------
// LayerNorm over channels (channel-major layout), optional +qpe constant.
// qpe[c] = 1 if (c % 160) >= 80 else 0   (pos_embed of zeros)
// ---------------------------------------------------------------------------
template <int ADD_QPE>
__global__ __launch_bounds__(256) void ln_kernel(const float* __restrict__ in,
                                                 float* __restrict__ out,
                                                 const float* __restrict__ gam,
                                                 const float* __restrict__ bet) {
  int g = blockIdx.x * 256 + threadIdx.x;
  if (g >= NTOT) return;
  int img = g / P_, p = g - img * P_;
  const float* base = in + (size_t)img * C_ * P_ + p;
  float s = 0.f, s2 = 0.f;
  for (int c = 0; c < C_; ++c) {
    float v = base[(size_t)c * P_];
    s += v;
    s2 = fmaf(v, v, s2);
  }
  float mu = s * (1.f / C_);
  float var = s2 * (1.f / C_) - mu * mu;
  float rs = rsqrtf(var + 1e-5f);
  float* ob = out + (size_t)img * C_ * P_ + p;
  for (int c = 0; c < C_; ++c) {
    float v = base[(size_t)c * P_];
    float o = (v - mu) * rs * gam[c] + bet[c];
    if (ADD_QPE) {
      int cm = (c >= 160) ? c - 160 : c;
      if (cm >= 80) o += 1.f;
    }
    ob[(size_t)c * P_] = o;
  }
}

// ---------------------------------------------------------------------------
// Build kv context for both neighbors:
//   kv = (gather(x_neighbor, round(corr/4)) + pos_embed(frac)) * mask
// One block: 64 pixels x 4 channel-groups (80 ch each). blockIdx.y = l (0/1).
// ---------------------------------------------------------------------------
__global__ __launch_bounds__(256) void gather_kernel(const float* __restrict__ x,
                                                     const float* __restrict__ corr,
                                                     const float* __restrict__ homos,
                                                     float* __restrict__ kvA,
                                                     float* __restrict__ kvB) {
  __shared__ float invf[80];
  int tid = threadIdx.x;
  if (tid < 80) invf[tid] = expf(-(float)tid * 0.11512925464970229f);  // 10000^(-j/80)
  __syncthreads();

  int px_r = tid & 63, cg = tid >> 6;  // cg: 0..3 -> (comp, sin/cos)
  int g = blockIdx.x * 64 + px_r;      // 1050*64 == NTOT exactly
  int l = blockIdx.y;
  int img = g / P_, p = g - img * P_;
  int b = img / MM, mi = img - b * MM;
  int hh = p / W_, ww = p - hh * W_;
  int nbj = l ? (mi + 1) % MM : (mi + 5) % MM;

  size_t cb = ((((size_t)(b * MM + mi) * MM + nbj) * H_ + hh) * W_ + ww) * 2;
  float cx = corr[cb], cy = corr[cb + 1];
  float xf = cx * 0.25f, yf = cy * 0.25f;
  float xi = rintf(xf), yi = rintf(yf);  // round-half-even == jnp.round
  bool inb = (xi >= 0.f) && (xi < 100.f) && (yi >= 0.f) && (yi < 56.f);
  int xic = (int)fminf(fmaxf(xi, 0.f), 99.f);
  int yic = (int)fminf(fmaxf(yi, 0.f), 55.f);
  float px = ((float)xic + 0.5f) * 4.f, py = ((float)yic + 0.5f) * 4.f;
  const float* hm = homos + ((size_t)(b * MM + nbj) * MM + mi) * 9;
  float pr0 = hm[0] * px + hm[1] * py + hm[2];
  float pr1 = hm[3] * px + hm[4] * py + hm[5];
  float pr2 = hm[6] * px + hm[7] * py + hm[8];
  float rx = pr0 / pr2, ry = pr1 / pr2;
  float qx = ((float)ww + 0.5f) * 4.f, qy = ((float)hh + 0.5f) * 4.f;
  bool ok = (fabsf(rx - qx) < 6.f) && (fabsf(ry - qy) < 6.f);
  float mask = (inb && ok) ? 1.f : 0.f;

  int imgnb = b * MM + nbj;
  int srcp = yic * W_ + xic;
  const float* xsrc = x + (size_t)imgnb * C_ * P_ + srcp;
  float* outp = (l ? kvB : kvA) + (size_t)img * C_ * P_ + p;

  float fr = (cg >= 2) ? (yf - yi) : (xf - xi);
  int iscos = cg & 1;
  int c0 = cg * 80;
  for (int k = 0; k < 80; ++k) {
    float ang = fr * invf[k];
    float pe = iscos ? __cosf(ang) : __sinf(ang);
    float kv = xsrc[(size_t)(c0 + k) * P_];
    outp[(size_t)(c0 + k) * P_] = (kv + pe) * mask;
  }
}

// ---------------------------------------------------------------------------
// Raw per-head scores for ONE neighbor: sraw[hd*NTOT+g] = (q . k)/sqrt(32)
// ---------------------------------------------------------------------------
__global__ __launch_bounds__(256) void score_half_kernel(const float* __restrict__ qh,
                                                         const float* __restrict__ kh,
                                                         float* __restrict__ sraw) {
  int g = blockIdx.x * 256 + threadIdx.x;
  if (g >= NTOT) return;
  int img = g / P_, p = g - img * P_;
  size_t base = (size_t)img * C_ * P_ + p;
  const float* q = qh + base;
  const float* k = kh + base;
  const float sc = 0.17677669529663687f;  // 1/sqrt(32)
#pragma unroll
  for (int hd = 0; hd < NHEADS; ++hd) {
    float a = 0.f;
    for (int d = 0; d < 32; ++d) {
      size_t c = (size_t)(hd * 32 + d) * P_;
      a = fmaf(q[c], k[c], a);
    }
    sraw[(size_t)hd * NTOT + g] = a * sc;
  }
}

// ---------------------------------------------------------------------------
// In-place softmax over the neighbor pair: aw[i], aw[10*NTOT+i]
// ---------------------------------------------------------------------------
__global__ __launch_bounds__(256) void softmax_pair_kernel(float* __restrict__ aw) {
  int i = blockIdx.x * 256 + threadIdx.x;
  if (i >= NHEADS * NTOT) return;
  float a = aw[i], b = aw[(size_t)NHEADS * NTOT + i];
  float mx = fmaxf(a, b);
  float ea = __expf(a - mx), eb = __expf(b - mx);
  float inv = 1.f / (ea + eb);
  aw[i] = ea * inv;
  aw[(size_t)NHEADS * NTOT + i] = eb * inv;
}

// ---------------------------------------------------------------------------
// f32 GEMM: Out[co][p] = sum_ci W[ci][co] * A[ci][p]   (per image)
// Tile 64(co) x 64(p), K-step 32, 256 threads, 4x4 micro-tile.
// EPI: 0 plain | 1 +bias[co]+res | 2 attn combine (two A's, aw scales)
//      3 gated FF1 (two W col-blocks, writes a*gelu(g)) | 4 +res (no bias)
// ---------------------------------------------------------------------------
template <int EPI>
__global__ __launch_bounds__(256) void gemm_f32(const float* __restrict__ Wm,
                                                const float* __restrict__ A0,
                                                const float* __restrict__ A1,
                                                float* __restrict__ Out,
                                                const float* __restrict__ bias,
                                                const float* __restrict__ res,
                                                const float* __restrict__ aw,
                                                int K, int ldw, int CinTot, int CoTot) {
  __shared__ float Wt[32][64];
  __shared__ float Wt2[32][64];
  __shared__ float At[32][64];
  const int tid = threadIdx.x;
  const int co_r = tid >> 4;  // 0..15
  const int p_r = tid & 15;   // 0..15
  const int p0 = blockIdx.x * 64, co0 = blockIdx.y * 64;
  const int img = blockIdx.z;
  const bool edge = (p0 + 64 > P_);
  float acc0[4][4] = {{0.f}};
  float acc1[4][4] = {{0.f}};

  auto stageW = [&](const float* Wsrc, float(*T)[64], int k0, int cofs) {
#pragma unroll
    for (int it = 0; it < 2; ++it) {
      int idx = tid + it * 256;
      int row = idx >> 4, c4 = (idx & 15) * 4;
      const float4 v = *reinterpret_cast<const float4*>(
          &Wsrc[(size_t)(k0 + row) * ldw + co0 + cofs + c4]);
      *reinterpret_cast<float4*>(&T[row][c4]) = v;
    }
  };
  auto stageA = [&](const float* Asrc, int k0) {
#pragma unroll
    for (int it = 0; it < 2; ++it) {
      int idx = tid + it * 256;
      int row = idx >> 4, c4 = (idx & 15) * 4;
      const float* src = &Asrc[((size_t)img * CinTot + k0 + row) * P_ + p0 + c4];
      if (!edge) {
        *reinterpret_cast<float4*>(&At[row][c4]) = *reinterpret_cast<const float4*>(src);
      } else {
        float t0 = (p0 + c4 + 0 < P_) ? src[0] : 0.f;
        float t1 = (p0 + c4 + 1 < P_) ? src[1] : 0.f;
        float t2 = (p0 + c4 + 2 < P_) ? src[2] : 0.f;
        float t3 = (p0 + c4 + 3 < P_) ? src[3] : 0.f;
        *reinterpret_cast<float4*>(&At[row][c4]) = make_float4(t0, t1, t2, t3);
      }
    }
  };
  auto compute = [&](float(&acc)[4][4], float(*T)[64]) {
#pragma unroll
    for (int kk = 0; kk < 32; ++kk) {
      float4 wf = *reinterpret_cast<const float4*>(&T[kk][co_r * 4]);
      float4 af = *reinterpret_cast<const float4*>(&At[kk][p_r * 4]);
      float we[4] = {wf.x, wf.y, wf.z, wf.w};
      float ae[4] = {af.x, af.y, af.z, af.w};
#pragma unroll
      for (int i = 0; i < 4; ++i)
#pragma unroll
        for (int j = 0; j < 4; ++j) acc[i][j] = fmaf(we[i], ae[j], acc[i][j]);
    }
  };

  if (EPI == 2) {
    for (int k0 = 0; k0 < K; k0 += 32) {
      stageW(Wm, Wt, k0, 0);
      stageA(A0, k0);
      __syncthreads();
      compute(acc0, Wt);
      __syncthreads();
    }
    for (int k0 = 0; k0 < K; k0 += 32) {
      stageW(Wm, Wt, k0, 0);
      stageA(A1, k0);
      __syncthreads();
      compute(acc1, Wt);
      __syncthreads();
    }
  } else if (EPI == 3) {
    for (int k0 = 0; k0 < K; k0 += 32) {
      stageW(Wm, Wt, k0, 0);
      stageW(Wm, Wt2, k0, 1280);
      stageA(A0, k0);
      __syncthreads();
      compute(acc0, Wt);
      compute(acc1, Wt2);
      __syncthreads();
    }
  } else {
    for (int k0 = 0; k0 < K; k0 += 32) {
      stageW(Wm, Wt, k0, 0);
      stageA(A0, k0);
      __syncthreads();
      compute(acc0, Wt);
      __syncthreads();
    }
  }

  // epilogue + store
#pragma unroll
  for (int i = 0; i < 4; ++i) {
    const int co = co0 + co_r * 4 + i;
    const int pb = p0 + p_r * 4;
    size_t orow = ((size_t)img * CoTot + co) * P_;
    float v[4];
    if (EPI == 0) {
#pragma unroll
      for (int j = 0; j < 4; ++j) v[j] = acc0[i][j];
    } else if (EPI == 1) {
      float b = bias[co];
      if (!edge) {
        float4 r = *reinterpret_cast<const float4*>(&res[orow + pb]);
        v[0] = acc0[i][0] + b + r.x;
        v[1] = acc0[i][1] + b + r.y;
        v[2] = acc0[i][2] + b + r.z;
        v[3] = acc0[i][3] + b + r.w;
      } else {
#pragma unroll
        for (int j = 0; j < 4; ++j)
          v[j] = (pb + j < P_) ? (acc0[i][j] + b + res[orow + pb + j]) : 0.f;
      }
    } else if (EPI == 2) {
      int hd = co >> 5;
      size_t ab = (size_t)hd * NTOT + (size_t)img * P_ + pb;
      size_t bb = (size_t)(NHEADS + hd) * NTOT + (size_t)img * P_ + pb;
      if (!edge) {
        float4 sa = *reinterpret_cast<const float4*>(&aw[ab]);
        float4 sb = *reinterpret_cast<const float4*>(&aw[bb]);
        v[0] = sa.x * acc0[i][0] + sb.x * acc1[i][0];
        v[1] = sa.y * acc0[i][1] + sb.y * acc1[i][1];
        v[2] = sa.z * acc0[i][2] + sb.z * acc1[i][2];
        v[3] = sa.w * acc0[i][3] + sb.w * acc1[i][3];
      } else {
#pragma unroll
        for (int j = 0; j < 4; ++j)
          v[j] = (pb + j < P_) ? (aw[ab + j] * acc0[i][j] + aw[bb + j] * acc1[i][j]) : 0.f;
      }
    } else if (EPI == 3) {  // a * gelu_exact(g)
      float ba = bias[co], bg = bias[co + 1280];
#pragma unroll
      for (int j = 0; j < 4; ++j) {
        float a = acc0[i][j] + ba;
        float gg = acc1[i][j] + bg;
        v[j] = a * (0.5f * gg * (1.f + erff(gg * 0.70710678118654752f)));
      }
    } else {  // EPI == 4: accumulate, no bias
      if (!edge) {
        float4 r = *reinterpret_cast<const float4*>(&res[orow + pb]);
        v[0] = acc0[i][0] + r.x;
        v[1] = acc0[i][1] + r.y;
        v[2] = acc0[i][2] + r.z;
        v[3] = acc0[i][3] + r.w;
      } else {
#pragma unroll
        for (int j = 0; j < 4; ++j)
          v[j] = (pb + j < P_) ? (acc0[i][j] + res[orow + pb + j]) : 0.f;
      }
    }
    if (!edge) {
      *reinterpret_cast<float4*>(&Out[orow + pb]) = make_float4(v[0], v[1], v[2], v[3]);
    } else {
#pragma unroll
      for (int j = 0; j < 4; ++j)
        if (pb + j < P_) Out[orow + pb + j] = v[j];
    }
  }
}

// ---------------------------------------------------------------------------
extern "C" void kernel_launch(void* const* d_in, const int* in_sizes, int n_in,
                              void* d_out, int out_size, void* d_ws, size_t ws_size,
                              hipStream_t stream) {
  const float* x = (const float*)d_in[0];
  const float* corr = (const float*)d_in[1];
  const float* homos = (const float*)d_in[2];
  const float* a1_wv = (const float*)d_in[5];
  const float* a1_wo = (const float*)d_in[6];
  const float* a1_bo = (const float*)d_in[7];
  const float* a2_wq = (const float*)d_in[8];
  const float* a2_wk = (const float*)d_in[9];
  const float* a2_wv = (const float*)d_in[10];
  const float* a2_wo = (const float*)d_in[11];
  const float* a2_bo = (const float*)d_in[12];
  const float* n1_g = (const float*)d_in[13];
  const float* n1_b = (const float*)d_in[14];
  const float* n2_g = (const float*)d_in[15];
  const float* n2_b = (const float*)d_in[16];
  const float* n3_g = (const float*)d_in[17];
  const float* n3_b = (const float*)d_in[18];
  const float* ff_w1 = (const float*)d_in[19];
  const float* ff_b1 = (const float*)d_in[20];
  const float* ff_w2 = (const float*)d_in[21];
  const float* ff_b2 = (const float*)d_in[22];
  float* out = (float*)d_out;

  // Resolve the static device workspace (no dependence on harness ws_size).
  void* wsp = nullptr;
  hipError_t werr = hipGetSymbolAddress(&wsp, HIP_SYMBOL(g_ws));
  float* ws = (werr == hipSuccess && wsp) ? (float*)wsp : (float*)d_ws;
  fprintf(stderr, "[kernel_launch] ws=%p (symbol err=%d) harness ws_size=%zu need=%zu\n",
          (void*)ws, (int)werr, ws_size, WS_FLOATS * sizeof(float));

  float* s0 = ws + 0 * SLOT;  // h1 -> h2 -> khA -> khB -> q2
  float* s1 = ws + 1 * SLOT;  // q1 -> h3
  float* s2 = ws + 2 * SLOT;  // kvA -> m_chunk
  float* s3 = ws + 3 * SLOT;  // kvB
  float* s4 = ws + 4 * SLOT;  // qh -> o -> FF2 accumulator
  float* aw = ws + 5 * SLOT;  // 2*10*NTOT raw scores -> softmaxed
  float* w1f = aw + (size_t)2 * NHEADS * NTOT;  // 320*320

  const dim3 blk(256);
  const dim3 gGemm(88, 5, NIMG);        // p-tiles x co-tiles(320/64) x images
  const int gPix = (NTOT + 255) / 256;  // 263

  // attn1 fused weight
  fuse_w1_kernel<<<320, 320, 0, stream>>>(a1_wv, a1_wo, w1f);
  // h1 = LN(x)*g1+b1 + qpe
  ln_kernel<1><<<gPix, blk, 0, stream>>>(x, s0, n1_g, n1_b);
  // q1 = W1f^T h1 + a1_bo + x
  gemm_f32<1><<<gGemm, blk, 0, stream>>>(w1f, s0, nullptr, s1, a1_bo, x, nullptr, 320, 320, 320, 320);
  // h2 = LN(q1)*g2+b2 + qpe
  ln_kernel<1><<<gPix, blk, 0, stream>>>(s1, s0, n2_g, n2_b);
  // kvA/kvB = gathered + pos-embedded + masked neighbor contexts
  gather_kernel<<<dim3(NTOT / 64, 2), blk, 0, stream>>>(x, corr, homos, s2, s3);
  // qh = wq^T h2 -> s4
  gemm_f32<0><<<gGemm, blk, 0, stream>>>(a2_wq, s0, nullptr, s4, nullptr, nullptr, nullptr, 320, 320, 320, 320);
  // khA = wk^T kvA -> s0 ; raw scores A
  gemm_f32<0><<<gGemm, blk, 0, stream>>>(a2_wk, s2, nullptr, s0, nullptr, nullptr, nullptr, 320, 320, 320, 320);
  score_half_kernel<<<gPix, blk, 0, stream>>>(s4, s0, aw);
  // khB = wk^T kvB -> s0 ; raw scores B
  gemm_f32<0><<<gGemm, blk, 0, stream>>>(a2_wk, s3, nullptr, s0, nullptr, nullptr, nullptr, 320, 320, 320, 320);
  score_half_kernel<<<gPix, blk, 0, stream>>>(s4, s0, aw + (size_t)NHEADS * NTOT);
  // softmax over the neighbor pair (in place)
  softmax_pair_kernel<<<(NHEADS * NTOT + 255) / 256, blk, 0, stream>>>(aw);
  // o = aA .* (wv^T kvA) + aB .* (wv^T kvB) -> s4 (qh dead)
  gemm_f32<2><<<gGemm, blk, 0, stream>>>(a2_wv, s2, s3, s4, nullptr, nullptr, aw, 320, 320, 320, 320);
  // q2 = wo^T o + a2_bo + q1 -> s0 (khB dead)
  gemm_f32<1><<<gGemm, blk, 0, stream>>>(a2_wo, s4, nullptr, s0, a2_bo, s1, nullptr, 320, 320, 320, 320);
  // h3 = LN(q2)*g3+b3 -> s1 (q1 dead)
  ln_kernel<0><<<gPix, blk, 0, stream>>>(s0, s1, n3_g, n3_b);
  // FF in 4 chunks of 320 rows of m; accumulate in s4; final chunk -> d_out
  for (int c = 0; c < 4; ++c) {
    // m_c = (ff_w1a_c^T h3 + b1a_c) * gelu(ff_w1g_c^T h3 + b1g_c) -> s2
    gemm_f32<3><<<gGemm, blk, 0, stream>>>(ff_w1 + c * 320, s1, nullptr, s2,
                                           ff_b1 + c * 320, nullptr, nullptr, 320, 2560, 320, 320);
    if (c == 0) {
      // s4 = W2_0^T m_0 + ff_b2 + q2
      gemm_f32<1><<<gGemm, blk, 0, stream>>>(ff_w2 + (size_t)c * 320 * 320, s2, nullptr, s4,
                                             ff_b2, s0, nullptr, 320, 320, 320, 320);
    } else if (c < 3) {
      // s4 += W2_c^T m_c
      gemm_f32<4><<<gGemm, blk, 0, stream>>>(ff_w2 + (size_t)c * 320 * 320, s2, nullptr, s4,
                                             nullptr, s4, nullptr, 320, 320, 320, 320);
    } else {
      // out = W2_3^T m_3 + s4   (single write to d_out)
      gemm_f32<4><<<gGemm, blk, 0, stream>>>(ff_w2 + (size_t)c * 320 * 320, s2, nullptr, out,
                                             nullptr, s4, nullptr, 320, 320, 320, 320);
    }
  }
}

// Round 5
// 1851.936 us; speedup vs baseline: 2.2769x; 2.2769x over previous
//
#include <hip/hip_runtime.h>
#include <cstdint>

#define C_ 320
#define H_ 56
#define W_ 100
#define P_ 5600
#define MM 6
#define NIMG 12
#define NTOT 67200
#define NHEADS 10

typedef unsigned short ushort_t;
typedef float f32x4 __attribute__((ext_vector_type(4)));
typedef unsigned int u32x4 __attribute__((ext_vector_type(4)));
typedef unsigned int u32x2 __attribute__((ext_vector_type(2)));

// ---------------------------------------------------------------------------
// Static device workspace (proven necessary in R4: harness d_ws too small).
// ---------------------------------------------------------------------------
__device__ __align__(256) unsigned char g_ws[611500032];

#define OFF_XT    0UL            // bf16 x token-major [g][320]
#define OFF_XTF   43008000UL     // f32  x token-major
#define OFF_H1    129024000UL    // bf16 h1
#define OFF_OTMP  0UL            // f32 attn partial (after xt dead)
#define OFF_M     0UL            // bf16 FF mid [g][1280] (after o_tmp dead)
#define OFF_KVA   172032000UL
#define OFF_KVB   215040000UL
#define OFF_Q1B   258048000UL
#define OFF_Q1F   301056000UL    // f32
#define OFF_H2    387072000UL    // later: o
#define OFF_QH    430080000UL    // later: q2b
#define OFF_KHA   473088000UL    // later: h3
#define OFF_KHB   516096000UL
#define OFF_Q2F   516096000UL    // f32 (overlaps khB, disjoint lifetime)
#define OFF_AW    602112000UL    // f32 [g][2][10]
#define OFF_WTMP  607488000UL
#define OFF_W1S   607897600UL
#define OFF_WQS   608102400UL
#define OFF_WKS   608307200UL
#define OFF_WVS   608512000UL
#define OFF_WOS   608716800UL
#define OFF_W1LS  608921600UL
#define OFF_W2LS  610560000UL

__device__ __forceinline__ ushort_t f2b(float f) {
  unsigned int u = __float_as_uint(f);
  return (ushort_t)((u + 0x7FFFu + ((u >> 16) & 1u)) >> 16);
}
__device__ __forceinline__ float b2f(ushort_t u) {
  return __uint_as_float(((unsigned int)u) << 16);
}
__device__ __forceinline__ unsigned int pack2(float lo, float hi) {
  return (unsigned int)f2b(lo) | ((unsigned int)f2b(hi) << 16);
}

// ---------------------------------------------------------------------------
// W1f[ci][co] = sum_k a1_wv[ci][k]*a1_wo[k][co]  (attn1 collapses; f32 tmp)
// ---------------------------------------------------------------------------
__global__ void fuse_w1_kernel(const float* __restrict__ wv,
                               const float* __restrict__ wo,
                               float* __restrict__ w1f) {
  int ci = blockIdx.x, co = threadIdx.x;
  float acc = 0.f;
  for (int k = 0; k < C_; ++k) acc = fmaf(wv[ci * C_ + k], wo[k * C_ + co], acc);
  w1f[ci * C_ + co] = acc;
}

// ---------------------------------------------------------------------------
// Swizzle weight [K][N] f32 -> bf16 MFMA B-fragment order.
// frag = kt*NF + nt; lane holds B[k=kt*32+(l>>4)*8+j][n=nt*16+(l&15)], j=0..7
// ---------------------------------------------------------------------------
__global__ void swz_w(const float* __restrict__ W, ushort_t* __restrict__ dst, int N) {
  int lane = threadIdx.x;
  int NF = N >> 4;
  int kt = blockIdx.x / NF, nt = blockIdx.x - kt * NF;
  int k0 = kt * 32 + (lane >> 4) * 8, n = nt * 16 + (lane & 15);
  unsigned int u[4];
#pragma unroll
  for (int i = 0; i < 4; ++i) {
    unsigned int lo = f2b(W[(size_t)(k0 + 2 * i) * N + n]);
    unsigned int hi = f2b(W[(size_t)(k0 + 2 * i + 1) * N + n]);
    u[i] = lo | (hi << 16);
  }
  *(u32x4*)(dst + ((size_t)blockIdx.x * 64 + lane) * 8) = (u32x4){u[0], u[1], u[2], u[3]};
}

// ---------------------------------------------------------------------------
// x [img][c][p] f32 -> xt bf16 + xtf f32, token-major [img*P+p][c]
// ---------------------------------------------------------------------------
__global__ __launch_bounds__(256) void transpose_x(const float* __restrict__ x,
                                                   ushort_t* __restrict__ xt,
                                                   float* __restrict__ xtf) {
  __shared__ float t[32][33];
  int p0 = blockIdx.x * 32, c0 = blockIdx.y * 32, img = blockIdx.z;
  int tid = threadIdx.x;
  {
    int ci = tid >> 3, pq = (tid & 7) * 4;
    const float* src = x + ((size_t)(img * C_ + c0 + ci)) * P_ + p0 + pq;
    float4 v = *(const float4*)src;
    t[ci][pq + 0] = v.x; t[ci][pq + 1] = v.y; t[ci][pq + 2] = v.z; t[ci][pq + 3] = v.w;
  }
  __syncthreads();
  {
    int p = tid >> 3, cq = (tid & 7) * 4;
    float a0 = t[cq + 0][p], a1 = t[cq + 1][p], a2 = t[cq + 2][p], a3 = t[cq + 3][p];
    size_t o = ((size_t)(img * P_ + p0 + p)) * C_ + c0 + cq;
    *(f32x4*)(xtf + o) = (f32x4){a0, a1, a2, a3};
    *(u32x2*)(xt + o) = (u32x2){pack2(a0, a1), pack2(a2, a3)};
  }
}

// ---------------------------------------------------------------------------
// LayerNorm token-major, wave per pixel; lanes 0..39 each own 8 channels.
// ---------------------------------------------------------------------------
template <int QPE>
__global__ __launch_bounds__(256) void ln_tok(const ushort_t* __restrict__ in,
                                              ushort_t* __restrict__ out,
                                              const float* __restrict__ gam,
                                              const float* __restrict__ bet) {
  int lane = threadIdx.x & 63, wid = threadIdx.x >> 6;
  size_t g = (size_t)blockIdx.x * 4 + wid;
  const ushort_t* row = in + g * C_;
  float v[8];
  float s = 0.f, s2 = 0.f;
  bool act = lane < 40;
  if (act) {
    u32x4 u = *(const u32x4*)(row + lane * 8);
#pragma unroll
    for (int i = 0; i < 4; ++i) {
      float lo = b2f((ushort_t)(u[i] & 0xFFFFu));
      float hi = b2f((ushort_t)(u[i] >> 16));
      v[2 * i] = lo; v[2 * i + 1] = hi;
      s += lo + hi;
      s2 = fmaf(lo, lo, fmaf(hi, hi, s2));
    }
  }
#pragma unroll
  for (int off = 32; off; off >>= 1) {
    s += __shfl_xor(s, off);
    s2 += __shfl_xor(s2, off);
  }
  float mu = s * (1.f / C_);
  float var = s2 * (1.f / C_) - mu * mu;
  float rs = rsqrtf(var + 1e-5f);
  if (act) {
    int c0 = lane * 8;
    float q = 0.f;
    if (QPE) q = ((lane / 10) & 1) ? 1.f : 0.f;
    float o[8];
#pragma unroll
    for (int j = 0; j < 8; ++j)
      o[j] = (v[j] - mu) * rs * gam[c0 + j] + bet[c0 + j] + q;
    u32x4 w = (u32x4){pack2(o[0], o[1]), pack2(o[2], o[3]), pack2(o[4], o[5]), pack2(o[6], o[7])};
    *(u32x4*)(out + g * C_ + c0) = w;
  }
}

// ---------------------------------------------------------------------------
// Gather + pos-embed + mask, token-major. Wave per (pixel, neighbor).
// ---------------------------------------------------------------------------
__global__ __launch_bounds__(256) void gather_tok(const ushort_t* __restrict__ xt,
                                                  const float* __restrict__ corr,
                                                  const float* __restrict__ homos,
                                                  ushort_t* __restrict__ kvA,
                                                  ushort_t* __restrict__ kvB) {
  __shared__ float invf[80];
  int tid = threadIdx.x;
  if (tid < 80) invf[tid] = expf(-(float)tid * 0.11512925464970229f);
  __syncthreads();
  int lane = tid & 63, wid = tid >> 6;
  int g = blockIdx.x * 4 + wid;
  int l = blockIdx.y;
  int img = g / P_, p = g - img * P_;
  int b = img / MM, mi = img - b * MM;
  int hh = p / W_, ww = p - hh * W_;
  int nbj = l ? (mi + 1) % MM : (mi + 5) % MM;

  size_t cb = ((((size_t)(b * MM + mi) * MM + nbj) * H_ + hh) * W_ + ww) * 2;
  float cx = corr[cb], cy = corr[cb + 1];
  float xf = cx * 0.25f, yf = cy * 0.25f;
  float xi = rintf(xf), yi = rintf(yf);
  bool inb = (xi >= 0.f) && (xi < 100.f) && (yi >= 0.f) && (yi < 56.f);
  int xic = (int)fminf(fmaxf(xi, 0.f), 99.f);
  int yic = (int)fminf(fmaxf(yi, 0.f), 55.f);
  float px = ((float)xic + 0.5f) * 4.f, py = ((float)yic + 0.5f) * 4.f;
  const float* hm = homos + ((size_t)(b * MM + nbj) * MM + mi) * 9;
  float pr0 = hm[0] * px + hm[1] * py + hm[2];
  float pr1 = hm[3] * px + hm[4] * py + hm[5];
  float pr2 = hm[6] * px + hm[7] * py + hm[8];
  float rx = pr0 / pr2, ry = pr1 / pr2;
  float qx = ((float)ww + 0.5f) * 4.f, qy = ((float)hh + 0.5f) * 4.f;
  bool ok = (fabsf(rx - qx) < 6.f) && (fabsf(ry - qy) < 6.f);
  float mask = (inb && ok) ? 1.f : 0.f;

  if (lane < 40) {
    int grp = lane / 10;
    float fr = (grp < 2) ? (xf - xi) : (yf - yi);
    int iscos = grp & 1;
    const float* iv = invf + (lane % 10) * 8;
    int nbimg = b * MM + nbj;
    int srcp = yic * W_ + xic;
    const ushort_t* src = xt + ((size_t)nbimg * P_ + srcp) * C_ + lane * 8;
    u32x4 u = *(const u32x4*)src;
    float o[8];
#pragma unroll
    for (int i = 0; i < 4; ++i) {
      float lo = b2f((ushort_t)(u[i] & 0xFFFFu));
      float hi = b2f((ushort_t)(u[i] >> 16));
      float a0 = fr * iv[2 * i], a1 = fr * iv[2 * i + 1];
      float p0v = iscos ? __cosf(a0) : __sinf(a0);
      float p1v = iscos ? __cosf(a1) : __sinf(a1);
      o[2 * i] = (lo + p0v) * mask;
      o[2 * i + 1] = (hi + p1v) * mask;
    }
    ushort_t* dst = (l ? kvB : kvA) + (size_t)g * C_ + lane * 8;
    *(u32x4*)dst = (u32x4){pack2(o[0], o[1]), pack2(o[2], o[3]), pack2(o[4], o[5]), pack2(o[6], o[7])};
  }
}

// ---------------------------------------------------------------------------
// Per-head scores for both neighbors + 2-way softmax. Wave per pixel.
// ---------------------------------------------------------------------------
__global__ __launch_bounds__(256) void score_tok(const ushort_t* __restrict__ qh,
                                                 const ushort_t* __restrict__ khA,
                                                 const ushort_t* __restrict__ khB,
                                                 float* __restrict__ aw) {
  int lane = threadIdx.x & 63, wid = threadIdx.x >> 6;
  size_t g = (size_t)blockIdx.x * 4 + wid;
  float dA = 0.f, dB = 0.f;
  if (lane < 40) {
    size_t base = g * C_ + lane * 8;
    u32x4 q = *(const u32x4*)(qh + base);
    u32x4 a = *(const u32x4*)(khA + base);
    u32x4 b = *(const u32x4*)(khB + base);
#pragma unroll
    for (int i = 0; i < 4; ++i) {
      float ql = b2f((ushort_t)(q[i] & 0xFFFFu)), qu = b2f((ushort_t)(q[i] >> 16));
      float al = b2f((ushort_t)(a[i] & 0xFFFFu)), au = b2f((ushort_t)(a[i] >> 16));
      float bl = b2f((ushort_t)(b[i] & 0xFFFFu)), bu = b2f((ushort_t)(b[i] >> 16));
      dA = fmaf(ql, al, fmaf(qu, au, dA));
      dB = fmaf(ql, bl, fmaf(qu, bu, dB));
    }
  }
  dA += __shfl_xor(dA, 1); dA += __shfl_xor(dA, 2);
  dB += __shfl_xor(dB, 1); dB += __shfl_xor(dB, 2);
  if (lane < 40 && (lane & 3) == 0) {
    int h = lane >> 2;
    const float sc = 0.17677669529663687f;
    float sa = dA * sc, sb = dB * sc;
    float mx = fmaxf(sa, sb);
    float ea = __expf(sa - mx), eb = __expf(sb - mx);
    float inv = 1.f / (ea + eb);
    aw[g * 20 + h] = ea * inv;
    aw[g * 20 + 10 + h] = eb * inv;
  }
}

// ---------------------------------------------------------------------------
// bf16 MFMA GEMM, token-major: Out[p][co] = sum_c A[p][c] * W[c][co]
// Block: 256 thr, tile 64p x 320co (FF1: 64p x (160a+160g)), BK=64, dbuf LDS.
// Waves: (mh = p-half, wn = n-half). Wave = 2 m-frags x 10 n-frags.
// EPI: 0 plain bf16 | 1 +bias+resf -> bf16+f32 | 2 *awA -> f32
//      3 *awB + resf -> bf16 | 4 FF1 a*gelu(g) -> bf16 | 6 FF2 -> f32 NCHW
// ---------------------------------------------------------------------------
template <int EPI>
__global__ __launch_bounds__(256) void gemm_tok(
    const ushort_t* __restrict__ A, const ushort_t* __restrict__ Wb,
    ushort_t* __restrict__ outb, float* __restrict__ outf,
    const float* __restrict__ bias, const float* __restrict__ resf,
    const float* __restrict__ aw, int Cin, int NS, int NF) {
  __shared__ ushort_t At[2][4096];
  const int tid = threadIdx.x;
  const int lane = tid & 63, wid = tid >> 6;
  const int mh = wid >> 1, wn = wid & 1;
  const int p0 = blockIdx.x * 64;
  const int img = blockIdx.y;
  const int by = blockIdx.z;
  const size_t rowbase = (size_t)img * P_ + p0;

  // staging: round rr covers rows rr*32..rr*32+31; thread = (row, slot)
  const int srow = tid >> 3;
  const int sslot = tid & 7;
  const int sphys = sslot ^ (srow & 7);
  const ushort_t* gsrc0 = A + (rowbase + srow) * (size_t)Cin + sslot * 8;
  const ushort_t* gsrc1 = A + (rowbase + 32 + srow) * (size_t)Cin + sslot * 8;
  const int ldst0 = srow * 64 + sphys * 8;
  const int ldst1 = (32 + srow) * 64 + sphys * 8;

  u32x4 st0 = *(const u32x4*)gsrc0;
  u32x4 st1 = *(const u32x4*)gsrc1;
  *(u32x4*)(&At[0][ldst0]) = st0;
  *(u32x4*)(&At[0][ldst1]) = st1;

  f32x4 acc[2][10];
#pragma unroll
  for (int m = 0; m < 2; ++m)
#pragma unroll
    for (int n = 0; n < 10; ++n) acc[m][n] = (f32x4){0.f, 0.f, 0.f, 0.f};

  // A-frag LDS offsets (ushort units)
  const int ar0 = (mh * 32 + (lane & 15)) * 64;
  const int ar1 = (mh * 32 + 16 + (lane & 15)) * 64;
  const int l7 = lane & 7, l4 = lane >> 4;

  int cur = 0;
  for (int s = 0; s < NS; ++s) {
    if (s + 1 < NS) {
      st0 = *(const u32x4*)(gsrc0 + (size_t)(s + 1) * 64);
      st1 = *(const u32x4*)(gsrc1 + (size_t)(s + 1) * 64);
    }
    __syncthreads();
#pragma unroll
    for (int kf = 0; kf < 2; ++kf) {
      const int kt = 2 * s + kf;
      const int ph = ((kf * 4 + l4) ^ l7) * 8;
      u32x4 a0 = *(const u32x4*)(&At[cur][ar0 + ph]);
      u32x4 a1 = *(const u32x4*)(&At[cur][ar1 + ph]);
#pragma unroll
      for (int n = 0; n < 10; ++n) {
        int nt;
        if (EPI == 4)
          nt = (n < 5) ? (by * 10 + wn * 5 + n) : (80 + by * 10 + wn * 5 + n - 5);
        else
          nt = wn * 10 + n;
        u32x4 b = *(const u32x4*)(Wb + ((size_t)(kt * NF + nt) * 64 + lane) * 8);
        asm("v_mfma_f32_16x16x32_bf16 %0, %1, %2, %0" : "+v"(acc[0][n]) : "v"(a0), "v"(b));
        asm("v_mfma_f32_16x16x32_bf16 %0, %1, %2, %0" : "+v"(acc[1][n]) : "v"(a1), "v"(b));
      }
    }
    if (s + 1 < NS) {
      *(u32x4*)(&At[cur ^ 1][ldst0]) = st0;
      *(u32x4*)(&At[cur ^ 1][ldst1]) = st1;
    }
    cur ^= 1;
  }
  asm volatile("s_nop 7\n\ts_nop 7");  // MFMA->VALU read hazard guard

  // ------------------------------ epilogue ------------------------------
  if constexpr (EPI == 6) {
    __shared__ float tbuf[32 * 321];
#pragma unroll 1
    for (int phse = 0; phse < 2; ++phse) {
      if (p0 + phse * 32 < P_) {
        if (mh == phse) {
#pragma unroll
          for (int m = 0; m < 2; ++m)
#pragma unroll
            for (int n = 0; n < 10; ++n)
#pragma unroll
              for (int r = 0; r < 4; ++r) {
                int lrow = m * 16 + (lane >> 4) * 4 + r;
                int co = wn * 160 + n * 16 + (lane & 15);
                size_t g = (size_t)img * P_ + p0 + phse * 32 + lrow;
                tbuf[lrow * 321 + co] = acc[m][n][r] + bias[co] + resf[g * C_ + co];
              }
        }
        __syncthreads();
#pragma unroll 1
        for (int pass = 0; pass < 2; ++pass) {
          int co = pass * 256 + tid;
          if (co < 320) {
            float vb[32];
#pragma unroll
            for (int pp = 0; pp < 32; ++pp) vb[pp] = tbuf[pp * 321 + co];
            float* dst = outf + ((size_t)img * C_ + co) * P_ + p0 + phse * 32;
#pragma unroll
            for (int qd = 0; qd < 8; ++qd)
              *(f32x4*)(dst + qd * 4) =
                  (f32x4){vb[4 * qd], vb[4 * qd + 1], vb[4 * qd + 2], vb[4 * qd + 3]};
          }
        }
        __syncthreads();
      }
    }
  } else {
    const int c15 = lane & 15, q4 = lane >> 4;
#pragma unroll
    for (int m = 0; m < 2; ++m) {
      const int pbase = p0 + mh * 32 + m * 16 + q4 * 4;
      if constexpr (EPI == 4) {
#pragma unroll
        for (int n = 0; n < 5; ++n) {
          int ja = by * 160 + wn * 80 + n * 16 + c15;
          float ba = bias[ja], bg = bias[1280 + ja];
#pragma unroll
          for (int r = 0; r < 4; ++r) {
            int p = pbase + r;
            if (p < P_) {
              float av = acc[m][n][r] + ba;
              float gv = acc[m][n + 5][r] + bg;
              float val = av * (0.5f * gv * (1.f + erff(gv * 0.70710678118654752f)));
              outb[((size_t)img * P_ + p) * 1280 + ja] = f2b(val);
            }
          }
        }
      } else {
#pragma unroll
        for (int n = 0; n < 10; ++n) {
          int co = wn * 160 + n * 16 + c15;
          int h = wn * 5 + (n >> 1);
#pragma unroll
          for (int r = 0; r < 4; ++r) {
            int p = pbase + r;
            if (p < P_) {
              size_t g = (size_t)img * P_ + p;
              float c = acc[m][n][r];
              if constexpr (EPI == 0) {
                outb[g * C_ + co] = f2b(c);
              } else if constexpr (EPI == 1) {
                float val = c + bias[co] + resf[g * C_ + co];
                outb[g * C_ + co] = f2b(val);
                outf[g * C_ + co] = val;
              } else if constexpr (EPI == 2) {
                outf[g * C_ + co] = aw[g * 20 + h] * c;
              } else if constexpr (EPI == 3) {
                float val = aw[g * 20 + 10 + h] * c + resf[g * C_ + co];
                outb[g * C_ + co] = f2b(val);
              }
            }
          }
        }
      }
    }
  }
}

// ---------------------------------------------------------------------------
extern "C" void kernel_launch(void* const* d_in, const int* in_sizes, int n_in,
                              void* d_out, int out_size, void* d_ws, size_t ws_size,
                              hipStream_t stream) {
  const float* x = (const float*)d_in[0];
  const float* corr = (const float*)d_in[1];
  const float* homos = (const float*)d_in[2];
  const float* a1_wv = (const float*)d_in[5];
  const float* a1_wo = (const float*)d_in[6];
  const float* a1_bo = (const float*)d_in[7];
  const float* a2_wq = (const float*)d_in[8];
  const float* a2_wk = (const float*)d_in[9];
  const float* a2_wv = (const float*)d_in[10];
  const float* a2_wo = (const float*)d_in[11];
  const float* a2_bo = (const float*)d_in[12];
  const float* n1_g = (const float*)d_in[13];
  const float* n1_b = (const float*)d_in[14];
  const float* n2_g = (const float*)d_in[15];
  const float* n2_b = (const float*)d_in[16];
  const float* n3_g = (const float*)d_in[17];
  const float* n3_b = (const float*)d_in[18];
  const float* ff_w1 = (const float*)d_in[19];
  const float* ff_b1 = (const float*)d_in[20];
  const float* ff_w2 = (const float*)d_in[21];
  const float* ff_b2 = (const float*)d_in[22];
  float* out = (float*)d_out;

  void* wsp = nullptr;
  if (hipGetSymbolAddress(&wsp, HIP_SYMBOL(g_ws)) != hipSuccess || !wsp) return;
  unsigned char* ws = (unsigned char*)wsp;
#define U16P(o) ((ushort_t*)(ws + (o)))
#define F32P(o) ((float*)(ws + (o)))

  const dim3 blk(256);
  const dim3 gG(88, NIMG, 1);

  // weight prep
  fuse_w1_kernel<<<320, 320, 0, stream>>>(a1_wv, a1_wo, F32P(OFF_WTMP));
  swz_w<<<200, 64, 0, stream>>>(F32P(OFF_WTMP), U16P(OFF_W1S), 320);
  swz_w<<<200, 64, 0, stream>>>(a2_wq, U16P(OFF_WQS), 320);
  swz_w<<<200, 64, 0, stream>>>(a2_wk, U16P(OFF_WKS), 320);
  swz_w<<<200, 64, 0, stream>>>(a2_wv, U16P(OFF_WVS), 320);
  swz_w<<<200, 64, 0, stream>>>(a2_wo, U16P(OFF_WOS), 320);
  swz_w<<<1600, 64, 0, stream>>>(ff_w1, U16P(OFF_W1LS), 2560);
  swz_w<<<800, 64, 0, stream>>>(ff_w2, U16P(OFF_W2LS), 320);

  // x -> token-major
  transpose_x<<<dim3(175, 10, NIMG), blk, 0, stream>>>(x, U16P(OFF_XT), F32P(OFF_XTF));
  // h1 = LN1(x) + qpe
  ln_tok<1><<<16800, blk, 0, stream>>>(U16P(OFF_XT), U16P(OFF_H1), n1_g, n1_b);
  // kv contexts
  gather_tok<<<dim3(16800, 2), blk, 0, stream>>>(U16P(OFF_XT), corr, homos,
                                                 U16P(OFF_KVA), U16P(OFF_KVB));
  // q1 = h1@W1f + bo + x   (bf16 + f32)
  gemm_tok<1><<<gG, blk, 0, stream>>>(U16P(OFF_H1), U16P(OFF_W1S), U16P(OFF_Q1B),
                                      F32P(OFF_Q1F), a1_bo, F32P(OFF_XTF), nullptr, 320, 5, 20);
  // h2 = LN2(q1) + qpe
  ln_tok<1><<<16800, blk, 0, stream>>>(U16P(OFF_Q1B), U16P(OFF_H2), n2_g, n2_b);
  // qh / khA / khB
  gemm_tok<0><<<gG, blk, 0, stream>>>(U16P(OFF_H2), U16P(OFF_WQS), U16P(OFF_QH),
                                      nullptr, nullptr, nullptr, nullptr, 320, 5, 20);
  gemm_tok<0><<<gG, blk, 0, stream>>>(U16P(OFF_KVA), U16P(OFF_WKS), U16P(OFF_KHA),
                                      nullptr, nullptr, nullptr, nullptr, 320, 5, 20);
  gemm_tok<0><<<gG, blk, 0, stream>>>(U16P(OFF_KVB), U16P(OFF_WKS), U16P(OFF_KHB),
                                      nullptr, nullptr, nullptr, nullptr, 320, 5, 20);
  // softmax weights
  score_tok<<<16800, blk, 0, stream>>>(U16P(OFF_QH), U16P(OFF_KHA), U16P(OFF_KHB),
                                       F32P(OFF_AW));
  // o = awA*(kvA@Wv) + awB*(kvB@Wv)
  gemm_tok<2><<<gG, blk, 0, stream>>>(U16P(OFF_KVA), U16P(OFF_WVS), nullptr,
                                      F32P(OFF_OTMP), nullptr, nullptr, F32P(OFF_AW), 320, 5, 20);
  gemm_tok<3><<<gG, blk, 0, stream>>>(U16P(OFF_KVB), U16P(OFF_WVS), U16P(OFF_H2),
                                      nullptr, nullptr, F32P(OFF_OTMP), F32P(OFF_AW), 320, 5, 20);
  // q2 = o@Wo + bo + q1
  gemm_tok<1><<<gG, blk, 0, stream>>>(U16P(OFF_H2), U16P(OFF_WOS), U16P(OFF_QH),
                                      F32P(OFF_Q2F), a2_bo, F32P(OFF_Q1F), nullptr, 320, 5, 20);
  // h3 = LN3(q2)
  ln_tok<0><<<16800, blk, 0, stream>>>(U16P(OFF_QH), U16P(OFF_KHA), n3_g, n3_b);
  // m = a * gelu(g)
  gemm_tok<4><<<dim3(88, NIMG, 8), blk, 0, stream>>>(U16P(OFF_KHA), U16P(OFF_W1LS),
                                                     U16P(OFF_M), nullptr, ff_b1, nullptr,
                                                     nullptr, 320, 5, 160);
  // out = m@W2 + b2 + q2   (f32, channel-major, direct to d_out)
  gemm_tok<6><<<gG, blk, 0, stream>>>(U16P(OFF_M), U16P(OFF_W2LS), nullptr, out,
                                      ff_b2, F32P(OFF_Q2F), nullptr, 1280, 20, 20);
}